// Round 6
// baseline (888.603 us; speedup 1.0000x reference)
//
#include <hip/hip_runtime.h>

// TTGNN: 2-layer GAT-style transformer conv, N=20000, E=120000, D=1024, H=8, C=128.
// R9: head-parallel attn (block=node, 4 waves, 4ch/lane) — WIN (attn off top-5).
// R10: GEMM rewritten as 8-phase 256x256 schedule (HK/m201 template, plain HIP):
//   - BK=64, 8 waves (2Mx4N), per-wave 128x64 out, acc[8][4] f32x4.
//   - 128KB double-buffered dynamic LDS; staging via global_load_lds with
//     PRE-SWIZZLED global source (linear LDS dest) + XOR'd ds_read (T2 variant:
//     slot ^= r.bit2<<1 | r.bit3 -> 16->4-way bank conflict).
//   - 4 phases/K-tile (quadrants Q00,Q01,Q11,Q10), 2 raw s_barriers per phase,
//     stages for tile t+1 issued at ph0, single counted-drain vmcnt(0) at ph3
//     (loads fly across ~3 phases; no __syncthreads full-drain anywhere).
//   - T5 setprio(1) around each 16-MFMA cluster; bijective XCD swizzle.

#define NN 20000
#define NE 120000
#define DD 1024
#define NH 8

typedef __attribute__((ext_vector_type(4))) float f32x4;
typedef __bf16 bf16x8 __attribute__((ext_vector_type(8)));

__device__ __forceinline__ unsigned short f2bf(float f) {
  unsigned int u = __float_as_uint(f);
  u += 0x7FFFu + ((u >> 16) & 1u);   // round-to-nearest-even
  return (unsigned short)(u >> 16);
}
__device__ __forceinline__ void unpack4(uint2 u, float* f) {
  f[0] = __uint_as_float(u.x << 16); f[1] = __uint_as_float(u.x & 0xFFFF0000u);
  f[2] = __uint_as_float(u.y << 16); f[3] = __uint_as_float(u.y & 0xFFFF0000u);
}

// ---------------- CSR build ----------------

__global__ __launch_bounds__(256) void count_kernel(
    const int* __restrict__ EI, const int* __restrict__ eattr, int* __restrict__ cnt) {
  int e = blockIdx.x * 256 + threadIdx.x;
  if (e < NE) {
    int d = EI[NE + e];
    int t = eattr[e];
    atomicAdd(&cnt[d * 5 + t], 1);
  }
}

__global__ __launch_bounds__(1024) void scan_kernel(
    const int* __restrict__ cnt, int* __restrict__ rowptr, int* __restrict__ cursor) {
  __shared__ int wsum[16];
  __shared__ int carry_s;
  int tid = threadIdx.x, lane = tid & 63, wv = tid >> 6;
  if (tid == 0) carry_s = 0;
  __syncthreads();
  for (int base = 0; base < NN; base += 1024) {
    int n = base + tid;
    int d = 0;
    if (n < NN) {
      const int* c = cnt + n * 5;
      d = c[0] + c[1] + c[2] + c[3] + c[4];
    }
    int v = d;
    #pragma unroll
    for (int off = 1; off < 64; off <<= 1) {
      int t = __shfl_up(v, off);
      if (lane >= off) v += t;
    }
    if (lane == 63) wsum[wv] = v;
    __syncthreads();
    int woff = 0;
    #pragma unroll
    for (int w = 0; w < 16; ++w) if (w < wv) woff += wsum[w];
    int carry = carry_s;
    int excl = carry + woff + v - d;
    if (n < NN) { rowptr[n] = excl; cursor[n] = excl; }
    __syncthreads();
    if (tid == 0) {
      int t = 0;
      #pragma unroll
      for (int w = 0; w < 16; ++w) t += wsum[w];
      carry_s = carry + t;
    }
    __syncthreads();
  }
  if (tid == 0) rowptr[NN] = carry_s;
}

__global__ __launch_bounds__(256) void scatter_kernel(
    const int* __restrict__ EI, const int* __restrict__ eattr,
    int* __restrict__ cursor, int* __restrict__ epk) {
  int e = blockIdx.x * 256 + threadIdx.x;
  if (e < NE) {
    int d = EI[NE + e];
    int s = EI[e];
    int t = eattr[e];
    int pos = atomicAdd(&cursor[d], 1);
    epk[pos] = (s << 3) | t;
  }
}

// ---------------- h0 = x + node_type_emb[node_types] ----------------

__global__ __launch_bounds__(256) void init_h_kernel(
    const float* __restrict__ x, const int* __restrict__ ntypes,
    const float* __restrict__ ntemb, float* __restrict__ h,
    unsigned short* __restrict__ hb) {
  int idx = blockIdx.x * 256 + threadIdx.x;
  int n = idx >> 8;
  int d4 = idx & 255;
  int t = ntypes[n];
  float4 xv = ((const float4*)x)[idx];
  float4 ev = ((const float4*)ntemb)[t * 256 + d4];
  float4 o;
  o.x = xv.x + ev.x; o.y = xv.y + ev.y; o.z = xv.z + ev.z; o.w = xv.w + ev.w;
  ((float4*)h)[idx] = o;
  ushort4 hv;
  hv.x = f2bf(o.x); hv.y = f2bf(o.y); hv.z = f2bf(o.z); hv.w = f2bf(o.w);
  ((ushort4*)hb)[idx] = hv;
}

// ---------------- weight transpose + bf16: WT[n][k] = bf16(W[k][n]) ----------------

__global__ __launch_bounds__(256) void transpose_w_kernel(
    const float* __restrict__ W, unsigned short* __restrict__ WT) {
  __shared__ float tile[32][33];
  int tx = threadIdx.x & 31, ty = threadIdx.x >> 5;
  int bx = blockIdx.x * 32;   // n base
  int by = blockIdx.y * 32;   // k base
  #pragma unroll
  for (int r = 0; r < 4; ++r)
    tile[ty + r * 8][tx] = W[(size_t)(by + ty + r * 8) * DD + bx + tx];
  __syncthreads();
  #pragma unroll
  for (int r = 0; r < 4; ++r)
    WT[(size_t)(bx + ty + r * 8) * DD + by + tx] = f2bf(tile[tx][ty + r * 8]);
}

// ---------------- M[t] = edge_type_emb[t] @ W_e[l]   (5 x 1024) ----------------

__global__ __launch_bounds__(256) void m_kernel(
    const float* __restrict__ ete, const float* __restrict__ We, float* __restrict__ M) {
  __shared__ float red[4][5][64];
  const int jl = threadIdx.x & 63;
  const int kc = threadIdx.x >> 6;          // wave-uniform
  const int j = blockIdx.x * 64 + jl;
  float acc[5] = {0.f, 0.f, 0.f, 0.f, 0.f};
  const int k0 = kc * 256;
  for (int k = k0; k < k0 + 256; ++k) {
    float w = We[(size_t)k * DD + j];
    #pragma unroll
    for (int t = 0; t < 5; ++t) acc[t] += ete[t * DD + k] * w;
  }
  #pragma unroll
  for (int t = 0; t < 5; ++t) red[kc][t][jl] = acc[t];
  __syncthreads();
  if (threadIdx.x < 64) {
    #pragma unroll
    for (int t = 0; t < 5; ++t)
      M[t * DD + blockIdx.x * 64 + threadIdx.x] =
          red[0][t][threadIdx.x] + red[1][t][threadIdx.x] +
          red[2][t][threadIdx.x] + red[3][t][threadIdx.x];
  }
}

// ---------------- 8-phase 256x256 bf16 MFMA GEMM (R10) ----------------
// A: bf16 [M][1024]. BT: bf16 [Ncols][1024] (B^T). K fixed = 1024 (16 tiles).
// LDS layout per buffer: A tile [256 rows][8 slots x 16B] then B tile same.
// Swizzle: data for (row r, col-slot s) stored at slot s ^ ((r>>2&1)<<1 | (r>>3&1)).
// Staging is linear-dest global_load_lds with the inverse swizzle folded into
// the per-lane GLOBAL address (both-sides rule, m104/m201).

__global__ __launch_bounds__(512, 2) void gemm256(
    const unsigned short* __restrict__ A, const unsigned short* __restrict__ BT,
    const float* __restrict__ bias0, const float* __restrict__ bias1,
    void* __restrict__ C0v, void* __restrict__ C1v,
    const float* __restrict__ resid, const float* __restrict__ gatep,
    int M, int mode) {
  extern __shared__ char smem[];          // 131072 B: [2 buf][A 32KB | B 32KB]
  const int tid = threadIdx.x;
  const int lane = tid & 63;
  const int wv = tid >> 6;                // 0..7
  const int wm = wv >> 2;                 // 0..1  (M half)
  const int wn = wv & 3;                  // 0..3  (N quarter)
  const int l15 = lane & 15, quad = lane >> 4;

  // bijective XCD swizzle (m204)
  const int nwg = gridDim.x * gridDim.y;
  const int lid = blockIdx.y * gridDim.x + blockIdx.x;
  const int q8 = nwg >> 3, r8 = nwg & 7;
  const int xcd = lid & 7, ixq = lid >> 3;
  const int swz = (xcd < r8 ? xcd * (q8 + 1) : r8 * (q8 + 1) + (xcd - r8) * q8) + ixq;
  const int bm = swz / gridDim.x, bn = swz % gridDim.x;
  const int row0 = bm * 256, col0 = bn * 256;

  // staging geometry: wave-issue (h,i) covers rows h*128 + (wv*2+i)*8 .. +8
  const int lr = lane >> 3;               // row within 8-row block
  const int sb = lane & 7;                // linear col slot (16B units)
  const int xb = (lane >> 5) & 1;         // = staged r_local bit2
  // read-side swizzle xor: r_local bits 2,3 come from l15
  const int rxor = (((lane >> 2) & 1) << 1) | ((lane >> 3) & 1);

  f32x4 acc[8][4];
  #pragma unroll
  for (int mt = 0; mt < 8; ++mt)
    #pragma unroll
    for (int nt = 0; nt < 4; ++nt) {
      f32x4 z = {0.f, 0.f, 0.f, 0.f};
      acc[mt][nt] = z;
    }
  bf16x8 aF[4][2];        // current M-half frags
  bf16x8 bF[2][2][2];     // both N-halves kept live

  auto stage = [&](int kt, int db) {
    char* base = smem + db * 65536;
    #pragma unroll
    for (int h = 0; h < 2; ++h) {
      #pragma unroll
      for (int i = 0; i < 2; ++i) {
        const int bi = wv * 2 + i;
        const int rloc = h * 128 + bi * 8 + lr;
        const int csl = ((sb ^ (xb << 1) ^ i) << 3);   // pre-swizzled col (elems)
        int ra = row0 + rloc; if (ra > M - 1) ra = M - 1;
        __builtin_amdgcn_global_load_lds(
            (const __attribute__((address_space(1))) unsigned int*)(A + (size_t)ra * 1024 + kt * 64 + csl),
            (__attribute__((address_space(3))) unsigned int*)(base + h * 16384 + bi * 1024), 16, 0, 0);
        const int rb = col0 + rloc;                    // N % 256 == 0: no clamp
        __builtin_amdgcn_global_load_lds(
            (const __attribute__((address_space(1))) unsigned int*)(BT + (size_t)rb * 1024 + kt * 64 + csl),
            (__attribute__((address_space(3))) unsigned int*)(base + 32768 + h * 16384 + bi * 1024), 16, 0, 0);
      }
    }
  };
  auto readA = [&](int db, int mh) {
    const char* Ab = smem + db * 65536;
    #pragma unroll
    for (int mt = 0; mt < 4; ++mt) {
      const int rl = wm * 128 + mh * 64 + mt * 16 + l15;
      #pragma unroll
      for (int kk = 0; kk < 2; ++kk) {
        const int sp = (kk * 4 + quad) ^ rxor;
        aF[mt][kk] = *(const bf16x8*)(Ab + rl * 128 + sp * 16);
      }
    }
  };
  auto readB = [&](int db, int nh) {
    const char* Bb = smem + db * 65536 + 32768;
    #pragma unroll
    for (int nt = 0; nt < 2; ++nt) {
      const int rl = wn * 64 + nh * 32 + nt * 16 + l15;
      #pragma unroll
      for (int kk = 0; kk < 2; ++kk) {
        const int sp = (kk * 4 + quad) ^ rxor;
        bF[nh][nt][kk] = *(const bf16x8*)(Bb + rl * 128 + sp * 16);
      }
    }
  };
  auto mfmaQ = [&](int a, int b) {
    __builtin_amdgcn_s_setprio(1);
    #pragma unroll
    for (int mt = 0; mt < 4; ++mt)
      #pragma unroll
      for (int nt = 0; nt < 2; ++nt)
        #pragma unroll
        for (int kk = 0; kk < 2; ++kk)
          acc[a * 4 + mt][b * 2 + nt] = __builtin_amdgcn_mfma_f32_16x16x32_bf16(
              aF[mt][kk], bF[b][nt][kk], acc[a * 4 + mt][b * 2 + nt], 0, 0, 0);
    __builtin_amdgcn_s_setprio(0);
  };

#define SBAR() { __builtin_amdgcn_s_barrier(); asm volatile("" ::: "memory"); }

  // prologue: stage tile 0, drain, rendezvous
  stage(0, 0);
  asm volatile("s_waitcnt vmcnt(0)" ::: "memory");
  SBAR();

  for (int kt = 0; kt < 16; ++kt) {
    const int cb = kt & 1;
    // ph0: reads of buf[cb] are gated by previous tile's ph3 {vmcnt; barrier}
    readA(cb, 0);
    readB(cb, 0);
    if (kt < 15) stage(kt + 1, cb ^ 1);
    SBAR();
    mfmaQ(0, 0);
    SBAR();
    // ph1
    readB(cb, 1);
    SBAR();
    mfmaQ(0, 1);
    SBAR();
    // ph2
    readA(cb, 1);
    SBAR();
    mfmaQ(1, 1);
    SBAR();
    // ph3: gate tile kt+1's staged data (issued at ph0, ~3 phases in flight)
    asm volatile("s_waitcnt vmcnt(0)" ::: "memory");
    SBAR();
    mfmaQ(1, 0);
    SBAR();
  }

  if (mode == 0) {
    #pragma unroll
    for (int mt = 0; mt < 8; ++mt) {
      #pragma unroll
      for (int r = 0; r < 4; ++r) {
        const int grow = row0 + wm * 128 + mt * 16 + quad * 4 + r;
        if (grow >= M) continue;
        #pragma unroll
        for (int nt = 0; nt < 4; ++nt) {
          const int cg = col0 + wn * 64 + nt * 16 + l15;
          const int half = cg >> 10;
          const int cl = cg & 1023;
          unsigned short* Cb = (unsigned short*)(half ? C1v : C0v);
          const float* bp = half ? bias1 : bias0;
          Cb[(size_t)grow * 1024 + cl] = f2bf(acc[mt][nt][r] + bp[cl]);
        }
      }
    }
  } else {
    float* Cp = (float*)C0v;
    const float g = gatep[0];
    #pragma unroll
    for (int mt = 0; mt < 8; ++mt) {
      #pragma unroll
      for (int r = 0; r < 4; ++r) {
        const int grow = row0 + wm * 128 + mt * 16 + quad * 4 + r;
        if (grow >= M) continue;
        #pragma unroll
        for (int nt = 0; nt < 4; ++nt) {
          const int cg = col0 + wn * 64 + nt * 16 + l15;
          float v = acc[mt][nt][r] + bias0[cg];
          Cp[(size_t)grow * 1024 + cg] = resid[(size_t)grow * 1024 + cg] + g * v;
        }
      }
    }
  }
}

// ---------------- fused attention, head-parallel (R9) ----------------
// Block = 256 threads = 1 node = 4 waves; wave wv owns heads 2wv,2wv+1;
// lane owns 4 channels (ch = wv*256 + lane*4). Logit reduce: 5 xor-shuffles
// within the 32-lane head half. Softmax without max-subtraction (bounded).
// LayerNorm via per-wave moments + 4-slot LDS cross-wave reduce.

__global__ __launch_bounds__(256) void attn_kernel(
    const unsigned short* __restrict__ xlb, const unsigned short* __restrict__ xrb,
    const int* __restrict__ rowptr, const int* __restrict__ epk,
    const int* __restrict__ cnt, const float* __restrict__ Mbuf,
    const float* __restrict__ attl, const float* __restrict__ biasl,
    const float* __restrict__ gammal, const float* __restrict__ betal,
    float* __restrict__ h, unsigned short* __restrict__ hb, int write_h) {
  __shared__ float red1[4], red2[4];
  const int lane = threadIdx.x & 63;
  const int wv = threadIdx.x >> 6;
  const int n = blockIdx.x;
  const int ch = wv * 256 + lane * 4;

  const int beg = rowptr[n], end = rowptr[n + 1];
  const int* c5 = cnt + n * 5;
  int c0 = c5[0], c1 = c5[1], c2 = c5[2], c3 = c5[3], c4 = c5[4];

  float xrf[4], attf[4];
  {
    uint2 a = *(const uint2*)(xrb + (size_t)n * DD + ch);
    unpack4(a, xrf);
    float4 t = *(const float4*)(attl + ch);
    attf[0] = t.x; attf[1] = t.y; attf[2] = t.z; attf[3] = t.w;
  }
  float acc0 = 0.f, acc1 = 0.f, acc2 = 0.f, acc3 = 0.f;
  float den = 0.f;

  for (int base = beg; base < end; base += 64) {
    int cc = min(64, end - base);
    int packed = 0;
    if (lane < cc) packed = epk[base + lane];
    for (int j = 0; j < cc; ++j) {
      int pk = __shfl(packed, j);
      int src = pk >> 3, at = pk & 7;
      uint2 v = *(const uint2*)(xlb + (size_t)src * DD + ch);
      float4 m = *(const float4*)(Mbuf + at * DD + ch);
      float vf[4];
      unpack4(v, vf);
      float s0 = vf[0] + xrf[0] + m.x; s0 = fmaxf(s0, 0.2f * s0);
      float s1 = vf[1] + xrf[1] + m.y; s1 = fmaxf(s1, 0.2f * s1);
      float s2 = vf[2] + xrf[2] + m.z; s2 = fmaxf(s2, 0.2f * s2);
      float s3 = vf[3] + xrf[3] + m.w; s3 = fmaxf(s3, 0.2f * s3);
      float lg = s0 * attf[0] + s1 * attf[1] + s2 * attf[2] + s3 * attf[3];
      lg += __shfl_xor(lg, 1);
      lg += __shfl_xor(lg, 2);
      lg += __shfl_xor(lg, 4);
      lg += __shfl_xor(lg, 8);
      lg += __shfl_xor(lg, 16);
      float p = __expf(lg);
      den += p;
      acc0 += p * vf[0]; acc1 += p * vf[1];
      acc2 += p * vf[2]; acc3 += p * vf[3];
    }
  }

  // self-loop: edge emb = mean of incoming edge-type embeddings
  {
    float inv = 1.f / fmaxf((float)(c0 + c1 + c2 + c3 + c4), 1.f);
    float w0 = c0 * inv, w1 = c1 * inv, w2 = c2 * inv, w3 = c3 * inv, w4 = c4 * inv;
    uint2 v = *(const uint2*)(xlb + (size_t)n * DD + ch);
    float vf[4];
    unpack4(v, vf);
    float4 m0 = *(const float4*)(Mbuf + 0 * DD + ch);
    float4 m1 = *(const float4*)(Mbuf + 1 * DD + ch);
    float4 m2 = *(const float4*)(Mbuf + 2 * DD + ch);
    float4 m3 = *(const float4*)(Mbuf + 3 * DD + ch);
    float4 m4 = *(const float4*)(Mbuf + 4 * DD + ch);
    float e0 = w0 * m0.x + w1 * m1.x + w2 * m2.x + w3 * m3.x + w4 * m4.x;
    float e1 = w0 * m0.y + w1 * m1.y + w2 * m2.y + w3 * m3.y + w4 * m4.y;
    float e2 = w0 * m0.z + w1 * m1.z + w2 * m2.z + w3 * m3.z + w4 * m4.z;
    float e3 = w0 * m0.w + w1 * m1.w + w2 * m2.w + w3 * m3.w + w4 * m4.w;
    float s0 = vf[0] + xrf[0] + e0; s0 = fmaxf(s0, 0.2f * s0);
    float s1 = vf[1] + xrf[1] + e1; s1 = fmaxf(s1, 0.2f * s1);
    float s2 = vf[2] + xrf[2] + e2; s2 = fmaxf(s2, 0.2f * s2);
    float s3 = vf[3] + xrf[3] + e3; s3 = fmaxf(s3, 0.2f * s3);
    float lg = s0 * attf[0] + s1 * attf[1] + s2 * attf[2] + s3 * attf[3];
    lg += __shfl_xor(lg, 1);
    lg += __shfl_xor(lg, 2);
    lg += __shfl_xor(lg, 4);
    lg += __shfl_xor(lg, 8);
    lg += __shfl_xor(lg, 16);
    float p = __expf(lg);
    den += p;
    acc0 += p * vf[0]; acc1 += p * vf[1];
    acc2 += p * vf[2]; acc3 += p * vf[3];
  }

  // epilogue: alpha-normalize + bias + ELU + residual + LayerNorm (cross-wave)
  float invd = 1.f / den;
  float4 b4 = *(const float4*)(biasl + ch);
  float4 h4 = *(const float4*)(h + (size_t)n * DD + ch);
  float o0 = acc0 * invd + b4.x;
  float o1 = acc1 * invd + b4.y;
  float o2 = acc2 * invd + b4.z;
  float o3 = acc3 * invd + b4.w;
  o0 = o0 > 0.f ? o0 : (__expf(o0) - 1.f);
  o1 = o1 > 0.f ? o1 : (__expf(o1) - 1.f);
  o2 = o2 > 0.f ? o2 : (__expf(o2) - 1.f);
  o3 = o3 > 0.f ? o3 : (__expf(o3) - 1.f);
  float y0 = o0 + h4.x, y1 = o1 + h4.y, y2 = o2 + h4.z, y3 = o3 + h4.w;
  float s1r = y0 + y1 + y2 + y3;
  float s2r = y0 * y0 + y1 * y1 + y2 * y2 + y3 * y3;
  #pragma unroll
  for (int off = 1; off < 64; off <<= 1) {
    s1r += __shfl_xor(s1r, off);
    s2r += __shfl_xor(s2r, off);
  }
  if (lane == 0) { red1[wv] = s1r; red2[wv] = s2r; }
  __syncthreads();
  float t1 = red1[0] + red1[1] + red1[2] + red1[3];
  float t2 = red2[0] + red2[1] + red2[2] + red2[3];
  float mu = t1 * (1.f / 1024.f);
  float var = t2 * (1.f / 1024.f) - mu * mu;
  float rs = rsqrtf(var + 1e-5f);
  {
    float4 g4 = *(const float4*)(gammal + ch);
    float4 be4 = *(const float4*)(betal + ch);
    float w0 = (y0 - mu) * rs * g4.x + be4.x;
    float w1 = (y1 - mu) * rs * g4.y + be4.y;
    float w2 = (y2 - mu) * rs * g4.z + be4.z;
    float w3 = (y3 - mu) * rs * g4.w + be4.w;
    if (write_h) {
      float4 o4; o4.x = w0; o4.y = w1; o4.z = w2; o4.w = w3;
      *(float4*)(h + (size_t)n * DD + ch) = o4;
    }
    uint2 pk;
    pk.x = (unsigned int)f2bf(w0) | ((unsigned int)f2bf(w1) << 16);
    pk.y = (unsigned int)f2bf(w2) | ((unsigned int)f2bf(w3) << 16);
    *(uint2*)(hb + (size_t)n * DD + ch) = pk;
  }
}

// ---------------- launcher ----------------

extern "C" void kernel_launch(void* const* d_in, const int* in_sizes, int n_in,
                              void* d_out, int out_size, void* d_ws, size_t ws_size,
                              hipStream_t stream) {
  (void)in_sizes; (void)n_in; (void)out_size; (void)ws_size;
  const float* x      = (const float*)d_in[0];
  const int*   EI     = (const int*)d_in[1];
  const int*   eattr  = (const int*)d_in[2];
  const int*   ntypes = (const int*)d_in[3];
  const float* ntemb  = (const float*)d_in[4];
  const float* etemb  = (const float*)d_in[5];
  const float* W_l    = (const float*)d_in[6];
  const float* b_l    = (const float*)d_in[7];
  const float* W_r    = (const float*)d_in[8];
  const float* b_r    = (const float*)d_in[9];
  const float* W_e    = (const float*)d_in[10];
  const float* att    = (const float*)d_in[11];
  const float* bias   = (const float*)d_in[12];
  const float* gamma  = (const float*)d_in[13];
  const float* beta   = (const float*)d_in[14];
  const float* W_out  = (const float*)d_in[15];
  const float* b_out  = (const float*)d_in[16];
  const float* gate   = (const float*)d_in[17];
  float* out = (float*)d_out;

  char* ws = (char*)d_ws;
  size_t off = 0;
  auto alloc = [&](size_t bytes) {
    char* p = ws + off;
    off = (off + bytes + 255) & ~(size_t)255;
    return p;
  };
  float*          h       = (float*)alloc((size_t)NN * DD * 4);
  unsigned short* hb      = (unsigned short*)alloc((size_t)NN * DD * 2);
  unsigned short* xlb     = (unsigned short*)alloc((size_t)NN * DD * 2);
  unsigned short* xrb     = (unsigned short*)alloc((size_t)NN * DD * 2);
  unsigned short* WTcat   = (unsigned short*)alloc((size_t)2 * DD * DD * 2);  // [W_l^T ; W_r^T]
  unsigned short* WT2     = (unsigned short*)alloc((size_t)DD * DD * 2);
  float*          Mbuf    = (float*)alloc((size_t)5 * DD * 4);
  int*            countb  = (int*)alloc((size_t)NN * 5 * 4);
  int*            rowptr  = (int*)alloc((size_t)(NN + 1) * 4);
  int*            cursor  = (int*)alloc((size_t)NN * 4);
  int*            epk     = (int*)alloc((size_t)NE * 4);

  static bool attr_done = false;
  if (!attr_done) {
    (void)hipFuncSetAttribute((const void*)gemm256,
                              hipFuncAttributeMaxDynamicSharedMemorySize, 131072);
    attr_done = true;
  }

  hipMemsetAsync(countb, 0, (size_t)NN * 5 * 4, stream);
  count_kernel<<<(NE + 255) / 256, 256, 0, stream>>>(EI, eattr, countb);
  scan_kernel<<<1, 1024, 0, stream>>>(countb, rowptr, cursor);
  scatter_kernel<<<(NE + 255) / 256, 256, 0, stream>>>(EI, eattr, cursor, epk);
  init_h_kernel<<<NN, 256, 0, stream>>>(x, ntypes, ntemb, h, hb);

  dim3 tgrid(DD / 32, DD / 32);
  dim3 g2(8, (NN + 255) / 256);   // dual GEMM: N=2048 -> 8 col tiles, 79 row tiles
  dim3 g1(4, (NN + 255) / 256);   // final GEMM: N=1024 -> 4 col tiles
  for (int l = 0; l < 2; ++l) {
    transpose_w_kernel<<<tgrid, 256, 0, stream>>>(W_l + (size_t)l * DD * DD, WTcat);
    transpose_w_kernel<<<tgrid, 256, 0, stream>>>(W_r + (size_t)l * DD * DD, WTcat + (size_t)DD * DD);
    m_kernel<<<DD / 64, 256, 0, stream>>>(etemb, W_e + (size_t)l * DD * DD, Mbuf);
    gemm256<<<g2, 512, 131072, stream>>>(hb, WTcat, b_l + l * DD, b_r + l * DD,
                                         xlb, xrb, nullptr, nullptr, NN, 0);
    attn_kernel<<<NN, 256, 0, stream>>>(xlb, xrb, rowptr, epk, countb, Mbuf,
                                        att + l * DD, bias + l * DD,
                                        gamma + l * DD, beta + l * DD, h, hb,
                                        l == 0 ? 1 : 0);
  }
  transpose_w_kernel<<<tgrid, 256, 0, stream>>>(W_out, WT2);
  gemm256<<<g1, 512, 131072, stream>>>(hb, WT2, b_out, nullptr,
                                       out, nullptr, x, gate, NN, 1);
}

// Round 7
// 751.137 us; speedup vs baseline: 1.1830x; 1.1830x over previous
//
#include <hip/hip_runtime.h>

// TTGNN: 2-layer GAT-style transformer conv, N=20000, E=120000, D=1024, H=8, C=128.
// R9:  head-parallel attn (block=node, 4 waves, 4ch/lane) — WIN.
// R10: 8-phase 256^2 GEMM port — REGRESSION (bank conflicts 2.3e7: swizzle wrong
//      for this lane->row mapping; 128KB LDS -> 1 block/CU lockstep). Reverted.
// R11: consolidation: (a) R9 gemm_bf16 restored (proven 125us); (b) CSR scan
//      parallelized (3-pass: 20-block reduce, 1-block partial scan, 20-block
//      final) replacing the single-block 20-iteration serial scan; (c) 5 weight
//      transposes batched into one grid.z=5 launch, both m_kernels into one
//      grid.z=2 launch, hoisted before the layer loop.

#define NN 20000
#define NE 120000
#define DD 1024
#define NH 8

typedef __attribute__((ext_vector_type(4))) float f32x4;
typedef __bf16 bf16x8 __attribute__((ext_vector_type(8)));

__device__ __forceinline__ unsigned short f2bf(float f) {
  unsigned int u = __float_as_uint(f);
  u += 0x7FFFu + ((u >> 16) & 1u);   // round-to-nearest-even
  return (unsigned short)(u >> 16);
}
__device__ __forceinline__ void unpack4(uint2 u, float* f) {
  f[0] = __uint_as_float(u.x << 16); f[1] = __uint_as_float(u.x & 0xFFFF0000u);
  f[2] = __uint_as_float(u.y << 16); f[3] = __uint_as_float(u.y & 0xFFFF0000u);
}

// ---------------- CSR build ----------------

__global__ __launch_bounds__(256) void count_kernel(
    const int* __restrict__ EI, const int* __restrict__ eattr, int* __restrict__ cnt) {
  int e = blockIdx.x * 256 + threadIdx.x;
  if (e < NE) {
    int d = EI[NE + e];
    int t = eattr[e];
    atomicAdd(&cnt[d * 5 + t], 1);
  }
}

// 3-pass parallel scan over node degrees (deg[n] = sum of cnt[n][0..4]).
__global__ __launch_bounds__(1024) void scan_reduce_kernel(
    const int* __restrict__ cnt, int* __restrict__ bsum) {
  __shared__ int ws[16];
  int tid = threadIdx.x, lane = tid & 63, wv = tid >> 6;
  int n = blockIdx.x * 1024 + tid;
  int d = 0;
  if (n < NN) {
    const int* c = cnt + n * 5;
    d = c[0] + c[1] + c[2] + c[3] + c[4];
  }
  int v = d;
  #pragma unroll
  for (int off = 1; off < 64; off <<= 1) v += __shfl_xor(v, off);
  if (lane == 0) ws[wv] = v;
  __syncthreads();
  if (tid == 0) {
    int t = 0;
    #pragma unroll
    for (int w = 0; w < 16; ++w) t += ws[w];
    bsum[blockIdx.x] = t;
  }
}

__global__ __launch_bounds__(64) void scan_partials_kernel(
    const int* __restrict__ bsum, int* __restrict__ boff, int* __restrict__ rowptr,
    int nblk) {
  if (threadIdx.x == 0) {
    int acc = 0;
    for (int b = 0; b < nblk; ++b) { boff[b] = acc; acc += bsum[b]; }
    rowptr[NN] = acc;
  }
}

__global__ __launch_bounds__(1024) void scan_final_kernel(
    const int* __restrict__ cnt, const int* __restrict__ boff,
    int* __restrict__ rowptr, int* __restrict__ cursor) {
  __shared__ int ws[16];
  int tid = threadIdx.x, lane = tid & 63, wv = tid >> 6;
  int n = blockIdx.x * 1024 + tid;
  int d = 0;
  if (n < NN) {
    const int* c = cnt + n * 5;
    d = c[0] + c[1] + c[2] + c[3] + c[4];
  }
  int v = d;
  #pragma unroll
  for (int off = 1; off < 64; off <<= 1) {
    int t = __shfl_up(v, off);
    if (lane >= off) v += t;
  }
  if (lane == 63) ws[wv] = v;
  __syncthreads();
  int woff = 0;
  #pragma unroll
  for (int w = 0; w < 16; ++w) if (w < wv) woff += ws[w];
  int excl = boff[blockIdx.x] + woff + v - d;
  if (n < NN) { rowptr[n] = excl; cursor[n] = excl; }
}

// Writes packed (src<<3)|etype directly (reads here are coalesced).
__global__ __launch_bounds__(256) void scatter_kernel(
    const int* __restrict__ EI, const int* __restrict__ eattr,
    int* __restrict__ cursor, int* __restrict__ epk) {
  int e = blockIdx.x * 256 + threadIdx.x;
  if (e < NE) {
    int d = EI[NE + e];
    int s = EI[e];
    int t = eattr[e];
    int pos = atomicAdd(&cursor[d], 1);
    epk[pos] = (s << 3) | t;
  }
}

// ---------------- h0 = x + node_type_emb[node_types] ----------------

__global__ __launch_bounds__(256) void init_h_kernel(
    const float* __restrict__ x, const int* __restrict__ ntypes,
    const float* __restrict__ ntemb, float* __restrict__ h,
    unsigned short* __restrict__ hb) {
  int idx = blockIdx.x * 256 + threadIdx.x;
  int n = idx >> 8;
  int d4 = idx & 255;
  int t = ntypes[n];
  float4 xv = ((const float4*)x)[idx];
  float4 ev = ((const float4*)ntemb)[t * 256 + d4];
  float4 o;
  o.x = xv.x + ev.x; o.y = xv.y + ev.y; o.z = xv.z + ev.z; o.w = xv.w + ev.w;
  ((float4*)h)[idx] = o;
  ushort4 hv;
  hv.x = f2bf(o.x); hv.y = f2bf(o.y); hv.z = f2bf(o.z); hv.w = f2bf(o.w);
  ((ushort4*)hb)[idx] = hv;
}

// ------- batched weight transpose + bf16: WT[n][k] = bf16(W[k][n]), 5 slices -------

__global__ __launch_bounds__(256) void transpose_all_kernel(
    const float* __restrict__ Wl, const float* __restrict__ Wr,
    const float* __restrict__ Wo,
    unsigned short* __restrict__ WT0, unsigned short* __restrict__ WT1,
    unsigned short* __restrict__ WT2) {
  const float* W;
  unsigned short* WT;
  switch (blockIdx.z) {
    case 0:  W = Wl;                    WT = WT0;                    break;
    case 1:  W = Wr;                    WT = WT0 + (size_t)DD * DD;  break;
    case 2:  W = Wl + (size_t)DD * DD;  WT = WT1;                    break;
    case 3:  W = Wr + (size_t)DD * DD;  WT = WT1 + (size_t)DD * DD;  break;
    default: W = Wo;                    WT = WT2;                    break;
  }
  __shared__ float tile[32][33];
  int tx = threadIdx.x & 31, ty = threadIdx.x >> 5;
  int bx = blockIdx.x * 32;   // n base
  int by = blockIdx.y * 32;   // k base
  #pragma unroll
  for (int r = 0; r < 4; ++r)
    tile[ty + r * 8][tx] = W[(size_t)(by + ty + r * 8) * DD + bx + tx];
  __syncthreads();
  #pragma unroll
  for (int r = 0; r < 4; ++r)
    WT[(size_t)(bx + ty + r * 8) * DD + by + tx] = f2bf(tile[tx][ty + r * 8]);
}

// ---------------- M[l][t] = edge_type_emb[t] @ W_e[l]   (2 x 5 x 1024) ----------------

__global__ __launch_bounds__(256) void m_kernel(
    const float* __restrict__ ete, const float* __restrict__ We_all,
    float* __restrict__ Mall) {
  const float* We = We_all + (size_t)blockIdx.z * DD * DD;
  float* M = Mall + (size_t)blockIdx.z * 5 * DD;
  __shared__ float red[4][5][64];
  const int jl = threadIdx.x & 63;
  const int kc = threadIdx.x >> 6;          // wave-uniform
  const int j = blockIdx.x * 64 + jl;
  float acc[5] = {0.f, 0.f, 0.f, 0.f, 0.f};
  const int k0 = kc * 256;
  for (int k = k0; k < k0 + 256; ++k) {
    float w = We[(size_t)k * DD + j];
    #pragma unroll
    for (int t = 0; t < 5; ++t) acc[t] += ete[t * DD + k] * w;
  }
  #pragma unroll
  for (int t = 0; t < 5; ++t) red[kc][t][jl] = acc[t];
  __syncthreads();
  if (threadIdx.x < 64) {
    #pragma unroll
    for (int t = 0; t < 5; ++t)
      M[t * DD + blockIdx.x * 64 + threadIdx.x] =
          red[0][t][threadIdx.x] + red[1][t][threadIdx.x] +
          red[2][t][threadIdx.x] + red[3][t][threadIdx.x];
  }
}

// ---------------- bf16 MFMA GEMM, global_load_lds staging (m97 structure) ----

__global__ __launch_bounds__(256) void gemm_bf16(
    const unsigned short* __restrict__ A, const unsigned short* __restrict__ BT,
    const float* __restrict__ bias0, const float* __restrict__ bias1,
    void* __restrict__ C0v, void* __restrict__ C1v,
    const float* __restrict__ resid, const float* __restrict__ gatep,
    int M, int mode) {
  __shared__ unsigned short lsA[128 * 32];
  __shared__ unsigned short lsB[128 * 32];
  const int tid = threadIdx.x;
  const int lane = tid & 63;
  const int wv = tid >> 6;
  const int wm = wv & 1, wn = wv >> 1;

  // T1: XCD swizzle. nwg % 8 == 0 for both launch shapes (2512, 1256).
  const int nwg = gridDim.x * gridDim.y;
  const int lid = blockIdx.y * gridDim.x + blockIdx.x;
  const int cpx = nwg >> 3;
  const int swz = (lid & 7) * cpx + (lid >> 3);
  const int bm = swz / gridDim.x, bn = swz % gridDim.x;

  const int row0 = bm * 128, col0 = bn * 128;
  const int l15 = lane & 15, quad = lane >> 4;

  f32x4 acc[4][4];
  #pragma unroll
  for (int mt = 0; mt < 4; ++mt)
    #pragma unroll
    for (int nt = 0; nt < 4; ++nt) {
      f32x4 z = {0.f, 0.f, 0.f, 0.f};
      acc[mt][nt] = z;
    }

  const int r_in = lane >> 2;            // 0..15
  const int kchunk = (lane & 3) * 8;     // bf16-element offset within 32-wide K

  for (int kk = 0; kk < DD; kk += 32) {
    #pragma unroll
    for (int j = 0; j < 2; ++j) {
      int r = wv * 32 + j * 16;                  // wave-uniform row base
      int gr = row0 + r + r_in;
      if (gr > M - 1) gr = M - 1;                // clamp tail (masked at store)
      const unsigned short* gpA = A + (size_t)gr * DD + kk + kchunk;
      __builtin_amdgcn_global_load_lds(
          (const __attribute__((address_space(1))) unsigned int*)gpA,
          (__attribute__((address_space(3))) unsigned int*)(lsA + r * 32), 16, 0, 0);
      const unsigned short* gpB = BT + (size_t)(col0 + r + r_in) * DD + kk + kchunk;
      __builtin_amdgcn_global_load_lds(
          (const __attribute__((address_space(1))) unsigned int*)gpB,
          (__attribute__((address_space(3))) unsigned int*)(lsB + r * 32), 16, 0, 0);
    }
    __syncthreads();
    bf16x8 af[4], bfr[4];
    #pragma unroll
    for (int mt = 0; mt < 4; ++mt)
      af[mt] = *(const bf16x8*)(lsA + (wm * 64 + mt * 16 + l15) * 32 + quad * 8);
    #pragma unroll
    for (int nt = 0; nt < 4; ++nt)
      bfr[nt] = *(const bf16x8*)(lsB + (wn * 64 + nt * 16 + l15) * 32 + quad * 8);
    #pragma unroll
    for (int mt = 0; mt < 4; ++mt)
      #pragma unroll
      for (int nt = 0; nt < 4; ++nt)
        acc[mt][nt] = __builtin_amdgcn_mfma_f32_16x16x32_bf16(af[mt], bfr[nt], acc[mt][nt], 0, 0, 0);
    __syncthreads();
  }

  if (mode == 0) {
    unsigned short* Cb = (unsigned short*)(bn < 8 ? C0v : C1v);
    const float* bp = (bn < 8) ? bias0 : bias1;
    int coff = (bn < 8) ? 0 : 1024;
    #pragma unroll
    for (int mt = 0; mt < 4; ++mt) {
      #pragma unroll
      for (int r = 0; r < 4; ++r) {
        int grow = row0 + wm * 64 + mt * 16 + quad * 4 + r;
        if (grow >= M) continue;
        #pragma unroll
        for (int nt = 0; nt < 4; ++nt) {
          int c = col0 - coff + wn * 64 + nt * 16 + l15;
          Cb[(size_t)grow * DD + c] = f2bf(acc[mt][nt][r] + bp[c]);
        }
      }
    }
  } else {
    float* Cp = (float*)C0v;
    float g = gatep[0];
    #pragma unroll
    for (int mt = 0; mt < 4; ++mt) {
      #pragma unroll
      for (int r = 0; r < 4; ++r) {
        int grow = row0 + wm * 64 + mt * 16 + quad * 4 + r;
        if (grow >= M) continue;
        #pragma unroll
        for (int nt = 0; nt < 4; ++nt) {
          int c = col0 + wn * 64 + nt * 16 + l15;
          float v = acc[mt][nt][r] + bias0[c];
          Cp[(size_t)grow * DD + c] = resid[(size_t)grow * DD + c] + g * v;
        }
      }
    }
  }
}

// ---------------- fused attention, head-parallel (R9) ----------------
// Block = 256 threads = 1 node = 4 waves; wave wv owns heads 2wv,2wv+1;
// lane owns 4 channels (ch = wv*256 + lane*4). Logit reduce: 5 xor-shuffles
// within the 32-lane head half. Softmax without max-subtraction (bounded).
// LayerNorm via per-wave moments + 4-slot LDS cross-wave reduce.

__global__ __launch_bounds__(256) void attn_kernel(
    const unsigned short* __restrict__ xlb, const unsigned short* __restrict__ xrb,
    const int* __restrict__ rowptr, const int* __restrict__ epk,
    const int* __restrict__ cnt, const float* __restrict__ Mbuf,
    const float* __restrict__ attl, const float* __restrict__ biasl,
    const float* __restrict__ gammal, const float* __restrict__ betal,
    float* __restrict__ h, unsigned short* __restrict__ hb, int write_h) {
  __shared__ float red1[4], red2[4];
  const int lane = threadIdx.x & 63;
  const int wv = threadIdx.x >> 6;
  const int n = blockIdx.x;
  const int ch = wv * 256 + lane * 4;

  const int beg = rowptr[n], end = rowptr[n + 1];
  const int* c5 = cnt + n * 5;
  int c0 = c5[0], c1 = c5[1], c2 = c5[2], c3 = c5[3], c4 = c5[4];

  float xrf[4], attf[4];
  {
    uint2 a = *(const uint2*)(xrb + (size_t)n * DD + ch);
    unpack4(a, xrf);
    float4 t = *(const float4*)(attl + ch);
    attf[0] = t.x; attf[1] = t.y; attf[2] = t.z; attf[3] = t.w;
  }
  float acc0 = 0.f, acc1 = 0.f, acc2 = 0.f, acc3 = 0.f;
  float den = 0.f;

  for (int base = beg; base < end; base += 64) {
    int cc = min(64, end - base);
    int packed = 0;
    if (lane < cc) packed = epk[base + lane];
    for (int j = 0; j < cc; ++j) {
      int pk = __shfl(packed, j);
      int src = pk >> 3, at = pk & 7;
      uint2 v = *(const uint2*)(xlb + (size_t)src * DD + ch);
      float4 m = *(const float4*)(Mbuf + at * DD + ch);
      float vf[4];
      unpack4(v, vf);
      float s0 = vf[0] + xrf[0] + m.x; s0 = fmaxf(s0, 0.2f * s0);
      float s1 = vf[1] + xrf[1] + m.y; s1 = fmaxf(s1, 0.2f * s1);
      float s2 = vf[2] + xrf[2] + m.z; s2 = fmaxf(s2, 0.2f * s2);
      float s3 = vf[3] + xrf[3] + m.w; s3 = fmaxf(s3, 0.2f * s3);
      float lg = s0 * attf[0] + s1 * attf[1] + s2 * attf[2] + s3 * attf[3];
      lg += __shfl_xor(lg, 1);
      lg += __shfl_xor(lg, 2);
      lg += __shfl_xor(lg, 4);
      lg += __shfl_xor(lg, 8);
      lg += __shfl_xor(lg, 16);
      float p = __expf(lg);
      den += p;
      acc0 += p * vf[0]; acc1 += p * vf[1];
      acc2 += p * vf[2]; acc3 += p * vf[3];
    }
  }

  // self-loop: edge emb = mean of incoming edge-type embeddings
  {
    float inv = 1.f / fmaxf((float)(c0 + c1 + c2 + c3 + c4), 1.f);
    float w0 = c0 * inv, w1 = c1 * inv, w2 = c2 * inv, w3 = c3 * inv, w4 = c4 * inv;
    uint2 v = *(const uint2*)(xlb + (size_t)n * DD + ch);
    float vf[4];
    unpack4(v, vf);
    float4 m0 = *(const float4*)(Mbuf + 0 * DD + ch);
    float4 m1 = *(const float4*)(Mbuf + 1 * DD + ch);
    float4 m2 = *(const float4*)(Mbuf + 2 * DD + ch);
    float4 m3 = *(const float4*)(Mbuf + 3 * DD + ch);
    float4 m4 = *(const float4*)(Mbuf + 4 * DD + ch);
    float e0 = w0 * m0.x + w1 * m1.x + w2 * m2.x + w3 * m3.x + w4 * m4.x;
    float e1 = w0 * m0.y + w1 * m1.y + w2 * m2.y + w3 * m3.y + w4 * m4.y;
    float e2 = w0 * m0.z + w1 * m1.z + w2 * m2.z + w3 * m3.z + w4 * m4.z;
    float e3 = w0 * m0.w + w1 * m1.w + w2 * m2.w + w3 * m3.w + w4 * m4.w;
    float s0 = vf[0] + xrf[0] + e0; s0 = fmaxf(s0, 0.2f * s0);
    float s1 = vf[1] + xrf[1] + e1; s1 = fmaxf(s1, 0.2f * s1);
    float s2 = vf[2] + xrf[2] + e2; s2 = fmaxf(s2, 0.2f * s2);
    float s3 = vf[3] + xrf[3] + e3; s3 = fmaxf(s3, 0.2f * s3);
    float lg = s0 * attf[0] + s1 * attf[1] + s2 * attf[2] + s3 * attf[3];
    lg += __shfl_xor(lg, 1);
    lg += __shfl_xor(lg, 2);
    lg += __shfl_xor(lg, 4);
    lg += __shfl_xor(lg, 8);
    lg += __shfl_xor(lg, 16);
    float p = __expf(lg);
    den += p;
    acc0 += p * vf[0]; acc1 += p * vf[1];
    acc2 += p * vf[2]; acc3 += p * vf[3];
  }

  // epilogue: alpha-normalize + bias + ELU + residual + LayerNorm (cross-wave)
  float invd = 1.f / den;
  float4 b4 = *(const float4*)(biasl + ch);
  float4 h4 = *(const float4*)(h + (size_t)n * DD + ch);
  float o0 = acc0 * invd + b4.x;
  float o1 = acc1 * invd + b4.y;
  float o2 = acc2 * invd + b4.z;
  float o3 = acc3 * invd + b4.w;
  o0 = o0 > 0.f ? o0 : (__expf(o0) - 1.f);
  o1 = o1 > 0.f ? o1 : (__expf(o1) - 1.f);
  o2 = o2 > 0.f ? o2 : (__expf(o2) - 1.f);
  o3 = o3 > 0.f ? o3 : (__expf(o3) - 1.f);
  float y0 = o0 + h4.x, y1 = o1 + h4.y, y2 = o2 + h4.z, y3 = o3 + h4.w;
  float s1r = y0 + y1 + y2 + y3;
  float s2r = y0 * y0 + y1 * y1 + y2 * y2 + y3 * y3;
  #pragma unroll
  for (int off = 1; off < 64; off <<= 1) {
    s1r += __shfl_xor(s1r, off);
    s2r += __shfl_xor(s2r, off);
  }
  if (lane == 0) { red1[wv] = s1r; red2[wv] = s2r; }
  __syncthreads();
  float t1 = red1[0] + red1[1] + red1[2] + red1[3];
  float t2 = red2[0] + red2[1] + red2[2] + red2[3];
  float mu = t1 * (1.f / 1024.f);
  float var = t2 * (1.f / 1024.f) - mu * mu;
  float rs = rsqrtf(var + 1e-5f);
  {
    float4 g4 = *(const float4*)(gammal + ch);
    float4 be4 = *(const float4*)(betal + ch);
    float w0 = (y0 - mu) * rs * g4.x + be4.x;
    float w1 = (y1 - mu) * rs * g4.y + be4.y;
    float w2 = (y2 - mu) * rs * g4.z + be4.z;
    float w3 = (y3 - mu) * rs * g4.w + be4.w;
    if (write_h) {
      float4 o4; o4.x = w0; o4.y = w1; o4.z = w2; o4.w = w3;
      *(float4*)(h + (size_t)n * DD + ch) = o4;
    }
    uint2 pk;
    pk.x = (unsigned int)f2bf(w0) | ((unsigned int)f2bf(w1) << 16);
    pk.y = (unsigned int)f2bf(w2) | ((unsigned int)f2bf(w3) << 16);
    *(uint2*)(hb + (size_t)n * DD + ch) = pk;
  }
}

// ---------------- launcher ----------------

extern "C" void kernel_launch(void* const* d_in, const int* in_sizes, int n_in,
                              void* d_out, int out_size, void* d_ws, size_t ws_size,
                              hipStream_t stream) {
  (void)in_sizes; (void)n_in; (void)out_size; (void)ws_size;
  const float* x      = (const float*)d_in[0];
  const int*   EI     = (const int*)d_in[1];
  const int*   eattr  = (const int*)d_in[2];
  const int*   ntypes = (const int*)d_in[3];
  const float* ntemb  = (const float*)d_in[4];
  const float* etemb  = (const float*)d_in[5];
  const float* W_l    = (const float*)d_in[6];
  const float* b_l    = (const float*)d_in[7];
  const float* W_r    = (const float*)d_in[8];
  const float* b_r    = (const float*)d_in[9];
  const float* W_e    = (const float*)d_in[10];
  const float* att    = (const float*)d_in[11];
  const float* bias   = (const float*)d_in[12];
  const float* gamma  = (const float*)d_in[13];
  const float* beta   = (const float*)d_in[14];
  const float* W_out  = (const float*)d_in[15];
  const float* b_out  = (const float*)d_in[16];
  const float* gate   = (const float*)d_in[17];
  float* out = (float*)d_out;

  char* ws = (char*)d_ws;
  size_t off = 0;
  auto alloc = [&](size_t bytes) {
    char* p = ws + off;
    off = (off + bytes + 255) & ~(size_t)255;
    return p;
  };
  float*          h       = (float*)alloc((size_t)NN * DD * 4);
  unsigned short* hb      = (unsigned short*)alloc((size_t)NN * DD * 2);
  unsigned short* xlb     = (unsigned short*)alloc((size_t)NN * DD * 2);
  unsigned short* xrb     = (unsigned short*)alloc((size_t)NN * DD * 2);
  unsigned short* WTcat0  = (unsigned short*)alloc((size_t)2 * DD * DD * 2);  // layer0 [W_l^T ; W_r^T]
  unsigned short* WTcat1  = (unsigned short*)alloc((size_t)2 * DD * DD * 2);  // layer1
  unsigned short* WT2     = (unsigned short*)alloc((size_t)DD * DD * 2);
  float*          Mbuf    = (float*)alloc((size_t)2 * 5 * DD * 4);
  int*            countb  = (int*)alloc((size_t)NN * 5 * 4);
  int*            rowptr  = (int*)alloc((size_t)(NN + 1) * 4);
  int*            cursor  = (int*)alloc((size_t)NN * 4);
  int*            epk     = (int*)alloc((size_t)NE * 4);
  int*            bsum    = (int*)alloc((size_t)64 * 4);
  int*            boff    = (int*)alloc((size_t)64 * 4);

  const int nscan = (NN + 1023) / 1024;   // 20

  hipMemsetAsync(countb, 0, (size_t)NN * 5 * 4, stream);
  count_kernel<<<(NE + 255) / 256, 256, 0, stream>>>(EI, eattr, countb);
  scan_reduce_kernel<<<nscan, 1024, 0, stream>>>(countb, bsum);
  scan_partials_kernel<<<1, 64, 0, stream>>>(bsum, boff, rowptr, nscan);
  scan_final_kernel<<<nscan, 1024, 0, stream>>>(countb, boff, rowptr, cursor);
  scatter_kernel<<<(NE + 255) / 256, 256, 0, stream>>>(EI, eattr, cursor, epk);
  init_h_kernel<<<NN, 256, 0, stream>>>(x, ntypes, ntemb, h, hb);

  // precompute all weight transposes (5 slices) and both layers' M (one launch each)
  dim3 tgrid(DD / 32, DD / 32, 5);
  transpose_all_kernel<<<tgrid, 256, 0, stream>>>(W_l, W_r, W_out, WTcat0, WTcat1, WT2);
  m_kernel<<<dim3(DD / 64, 1, 2), 256, 0, stream>>>(etemb, W_e, Mbuf);

  dim3 ggrid2(16, (NN + 127) / 128);   // dual GEMM: N=2048, 2512 blocks (%8==0)
  dim3 ggrid1(8, (NN + 127) / 128);    // final GEMM: N=1024, 1256 blocks (%8==0)
  for (int l = 0; l < 2; ++l) {
    unsigned short* WTcat = l == 0 ? WTcat0 : WTcat1;
    gemm_bf16<<<ggrid2, 256, 0, stream>>>(hb, WTcat, b_l + l * DD, b_r + l * DD,
                                          xlb, xrb, nullptr, nullptr, NN, 0);
    attn_kernel<<<NN, 256, 0, stream>>>(xlb, xrb, rowptr, epk, countb,
                                        Mbuf + (size_t)l * 5 * DD,
                                        att + l * DD, bias + l * DD,
                                        gamma + l * DD, beta + l * DD, h, hb,
                                        l == 0 ? 1 : 0);
  }
  gemm_bf16<<<ggrid1, 256, 0, stream>>>(hb, WT2, b_out, nullptr,
                                        out, nullptr, x, gate, NN, 1);
}